// Round 1
// baseline (49749.286 us; speedup 1.0000x reference)
//
#include <hip/hip_runtime.h>

#define BATCH 1024
#define SEQ 512
#define NFEAT 24
#define NCELL 512
#define KTOT 536   // NFEAT + NCELL
#define KPAD 544   // padded to multiple of 32
#define ZC 2048    // 4 * NCELL
#define DENSE_N 2048
#define PRED_N 576

__device__ __forceinline__ float sigm(float x) { return 1.f / (1.f + __expf(-x)); }
__device__ __forceinline__ float ftanh(float x) {
    float t = __expf(-2.f * fabsf(x));
    float r = (1.f - t) / (1.f + t);
    return copysignf(r, x);
}

// One LSTM timestep: z = [x_t, h_in] @ W + b  (fused gates -> c, h_out)
// Tile: 64 batch rows x 128 z-cols (4 gates x 32 cells). Grid (16,16), 256 thr.
__global__ __launch_bounds__(256) void lstm_step(
    const float* __restrict__ X,     // [BATCH][SEQ][NFEAT]
    const float* __restrict__ W,     // [KTOT][ZC]
    const float* __restrict__ bias,  // [ZC]
    const float* __restrict__ h_in,  // [BATCH][NCELL]
    float* __restrict__ h_out,       // [BATCH][NCELL]
    float* __restrict__ c,           // [BATCH][NCELL] (in-place)
    int t)
{
    __shared__ float As[64][33];    // [row][kk]
    __shared__ float Bs[32][129];   // [kk][cl], cl = gate*32 + nl

    const int n0 = blockIdx.x * 32;   // cell-column block
    const int r0 = blockIdx.y * 64;   // batch-row block
    const int tid = (int)threadIdx.x;
    const int tx = tid & 31;          // cell col within block
    const int ty = tid >> 5;          // 8 row groups of 8 rows

    float acc[8][4];
    #pragma unroll
    for (int r = 0; r < 8; ++r) { acc[r][0]=0.f; acc[r][1]=0.f; acc[r][2]=0.f; acc[r][3]=0.f; }

    for (int k0 = 0; k0 < KPAD; k0 += 32) {
        // Stage A tile: 64 rows x 32 k (coalesced along k)
        #pragma unroll
        for (int i = 0; i < 8; ++i) {
            int e = tid + 256 * i;          // 0..2047
            int row = e >> 5, kk = e & 31;
            int k = k0 + kk;
            int gr = r0 + row;
            float v = 0.f;
            if (k < NFEAT)      v = X[(size_t)gr * (SEQ * NFEAT) + t * NFEAT + k];
            else if (k < KTOT)  v = h_in[(size_t)gr * NCELL + (k - NFEAT)];
            As[row][kk] = v;
        }
        // Stage B tile: 32 k x 128 cols (4 strided gate blocks, coalesced)
        #pragma unroll
        for (int i = 0; i < 16; ++i) {
            int e = tid + 256 * i;          // 0..4095
            int kk = e >> 7, cl = e & 127;
            int k = k0 + kk;
            int g = cl >> 5, nl = cl & 31;
            float v = 0.f;
            if (k < KTOT) v = W[(size_t)k * ZC + g * NCELL + n0 + nl];
            Bs[kk][cl] = v;
        }
        __syncthreads();
        #pragma unroll
        for (int kk = 0; kk < 32; ++kk) {
            float b0 = Bs[kk][tx], b1 = Bs[kk][32 + tx], b2 = Bs[kk][64 + tx], b3 = Bs[kk][96 + tx];
            #pragma unroll
            for (int r = 0; r < 8; ++r) {
                float a = As[ty * 8 + r][kk];
                acc[r][0] = fmaf(a, b0, acc[r][0]);
                acc[r][1] = fmaf(a, b1, acc[r][1]);
                acc[r][2] = fmaf(a, b2, acc[r][2]);
                acc[r][3] = fmaf(a, b3, acc[r][3]);
            }
        }
        __syncthreads();
    }

    // Fused gate epilogue. TF BasicLSTMCell order: i, j, f, o
    const int n = n0 + tx;
    const float bi = bias[n], bj = bias[NCELL + n], bf = bias[2 * NCELL + n], bo = bias[3 * NCELL + n];
    #pragma unroll
    for (int r = 0; r < 8; ++r) {
        int gr = r0 + ty * 8 + r;
        size_t idx = (size_t)gr * NCELL + n;
        float zi = acc[r][0] + bi;
        float zj = acc[r][1] + bj;
        float zf = acc[r][2] + bf;
        float zo = acc[r][3] + bo;
        float cn = c[idx] * sigm(zf + 1.0f) + sigm(zi) * ftanh(zj);
        c[idx] = cn;
        h_out[idx] = ftanh(cn) * sigm(zo);
    }
}

// Generic C = act(A @ Wm + bias). Tile 64x64, 256 threads, micro 4x4.
// Requires M%64==0, N%64==0, K%32==0.
template <int ACT>
__global__ __launch_bounds__(256) void gemm64(
    const float* __restrict__ A,   // [M][K]
    const float* __restrict__ Wm,  // [K][N]
    const float* __restrict__ bias,
    float* __restrict__ out,       // [M][N]
    int M, int N, int K)
{
    __shared__ float As[32][65];   // [kk][row]
    __shared__ float Bs[32][65];   // [kk][col]
    const int c0 = blockIdx.x * 64;
    const int r0 = blockIdx.y * 64;
    const int tid = (int)threadIdx.x;
    const int tx = tid & 15, ty = tid >> 4;

    float acc[4][4];
    #pragma unroll
    for (int r = 0; r < 4; ++r) { acc[r][0]=0.f; acc[r][1]=0.f; acc[r][2]=0.f; acc[r][3]=0.f; }

    for (int k0 = 0; k0 < K; k0 += 32) {
        #pragma unroll
        for (int i = 0; i < 8; ++i) {
            int e = tid + 256 * i;          // 0..2047
            int row = e >> 5, kk = e & 31;
            As[kk][row] = A[(size_t)(r0 + row) * K + k0 + kk];
        }
        #pragma unroll
        for (int i = 0; i < 8; ++i) {
            int e = tid + 256 * i;
            int kk = e >> 6, cl = e & 63;
            Bs[kk][cl] = Wm[(size_t)(k0 + kk) * N + c0 + cl];
        }
        __syncthreads();
        #pragma unroll
        for (int kk = 0; kk < 32; ++kk) {
            float b0 = Bs[kk][tx * 4], b1 = Bs[kk][tx * 4 + 1], b2 = Bs[kk][tx * 4 + 2], b3 = Bs[kk][tx * 4 + 3];
            #pragma unroll
            for (int r = 0; r < 4; ++r) {
                float a = As[kk][ty * 4 + r];
                acc[r][0] = fmaf(a, b0, acc[r][0]);
                acc[r][1] = fmaf(a, b1, acc[r][1]);
                acc[r][2] = fmaf(a, b2, acc[r][2]);
                acc[r][3] = fmaf(a, b3, acc[r][3]);
            }
        }
        __syncthreads();
    }
    #pragma unroll
    for (int r = 0; r < 4; ++r) {
        int gr = r0 + ty * 4 + r;
        #pragma unroll
        for (int j = 0; j < 4; ++j) {
            int gc = c0 + tx * 4 + j;
            float v = acc[r][j] + bias[gc];
            if (ACT) v = fmaxf(v, 0.f);
            out[(size_t)gr * N + gc] = v;
        }
    }
}

extern "C" void kernel_launch(void* const* d_in, const int* in_sizes, int n_in,
                              void* d_out, int out_size, void* d_ws, size_t ws_size,
                              hipStream_t stream)
{
    const float* X  = (const float*)d_in[0];
    const float* Wl = (const float*)d_in[1];
    const float* bl = (const float*)d_in[2];
    const float* Wd = (const float*)d_in[3];
    const float* bd = (const float*)d_in[4];
    const float* Wp = (const float*)d_in[5];
    const float* bp = (const float*)d_in[6];
    float* out = (float*)d_out;

    // Workspace layout (floats): c | h0 | h1 | dense  => 14 MB total
    float* c     = (float*)d_ws;
    float* h0    = c  + (size_t)BATCH * NCELL;
    float* h1    = h0 + (size_t)BATCH * NCELL;
    float* dense = h1 + (size_t)BATCH * NCELL;

    // Zero-init c and h0 (contiguous) every call — graph-safe.
    hipMemsetAsync(c, 0, sizeof(float) * (size_t)BATCH * NCELL * 2, stream);

    dim3 blk(256);
    dim3 g1(16, 16);  // 16 cell-col blocks x 16 row blocks
    for (int t = 0; t < SEQ; ++t) {
        const float* hin = (t & 1) ? h1 : h0;
        float*       hou = (t & 1) ? h0 : h1;
        lstm_step<<<g1, blk, 0, stream>>>(X, Wl, bl, hin, hou, c, t);
    }
    // Step 511 wrote h0 -> final hidden state.
    gemm64<1><<<dim3(DENSE_N / 64, BATCH / 64), blk, 0, stream>>>(h0, Wd, bd, dense, BATCH, DENSE_N, NCELL);
    gemm64<0><<<dim3(PRED_N / 64, BATCH / 64), blk, 0, stream>>>(dense, Wp, bp, out, BATCH, PRED_N, DENSE_N);
}

// Round 2
// 11094.131 us; speedup vs baseline: 4.4843x; 4.4843x over previous
//
#include <hip/hip_runtime.h>

#define BATCH 1024
#define SEQ 512
#define NFEAT 24
#define NCELL 512
#define ZC 2048      // 4*NCELL
#define KP 576       // padded/reordered K: [h(512) | x(24) | pad(40)]
#define NCH 18       // K chunks of 32
#define DENSE_N 2048
#define PRED_N 576

typedef unsigned short u16;
typedef unsigned short u16x8 __attribute__((ext_vector_type(8)));
typedef short s16x8 __attribute__((ext_vector_type(8)));
typedef float f32x4 __attribute__((ext_vector_type(4)));

__device__ __forceinline__ float sigm(float x) { return 1.f / (1.f + __expf(-x)); }
__device__ __forceinline__ float ftanh(float x) {
    float t = __expf(-2.f * fabsf(x));
    float r = (1.f - t) / (1.f + t);
    return copysignf(r, x);
}
__device__ __forceinline__ u16 f2b(float v) {           // f32 -> bf16 RTNE
    unsigned int x = __float_as_uint(v);
    unsigned int r = (x + 0x7fffu + ((x >> 16) & 1u)) >> 16;
    return (u16)r;
}
__device__ __forceinline__ float b2f(u16 u) { return __uint_as_float(((unsigned int)u) << 16); }

// ---------- prep: W -> transposed, K-reordered, split hi/lo ----------
__global__ __launch_bounds__(256) void prep_w(const float* __restrict__ W,
                                              u16* __restrict__ Whi, u16* __restrict__ Wlo) {
    int o = blockIdx.x * 256 + threadIdx.x;            // over ZC*KP
    if (o >= ZC * KP) return;
    int n = o / KP, k = o % KP;
    float v = 0.f;
    if (k < NCELL)            v = W[(size_t)(NFEAT + k) * ZC + n];     // h rows
    else if (k < NCELL + NFEAT) v = W[(size_t)(k - NCELL) * ZC + n];   // x rows
    u16 hi = f2b(v);
    u16 lo = f2b(v - b2f(hi));
    Whi[o] = hi; Wlo[o] = lo;
}

// ---------- prep: H0 = [h=0 | x_0 | 0], H1 = 0 ----------
__global__ __launch_bounds__(256) void prep_h(const float* __restrict__ X,
                                              u16* __restrict__ H0hi, u16* __restrict__ H0lo,
                                              u16* __restrict__ H1hi, u16* __restrict__ H1lo) {
    int o = blockIdx.x * 256 + threadIdx.x;            // over BATCH*KP
    if (o >= BATCH * KP) return;
    int row = o / KP, k = o % KP;
    u16 hi = 0, lo = 0;
    if (k >= NCELL && k < NCELL + NFEAT) {
        float v = X[(size_t)row * (SEQ * NFEAT) + (k - NCELL)];  // t = 0
        hi = f2b(v); lo = f2b(v - b2f(hi));
    }
    H0hi[o] = hi; H0lo[o] = lo;
    H1hi[o] = 0;  H1lo[o] = 0;
}

// ---------- LSTM step: z = A @ Wt^T via split-bf16 MFMA, fused gates ----------
// Grid (32, 8): x = cell-block (16 cells x 4 gates = 64 z-cols), y = row-block (128 rows).
__global__ __launch_bounds__(256) void lstm_step_mfma(
    const u16* __restrict__ Hhi, const u16* __restrict__ Hlo,   // [BATCH][KP]
    u16* __restrict__ Nhi, u16* __restrict__ Nlo,               // next-step A planes
    const u16* __restrict__ Wthi, const u16* __restrict__ Wtlo, // [ZC][KP]
    const float* __restrict__ bias,                             // [ZC]
    const float* __restrict__ X,                                // [BATCH][SEQ][NFEAT]
    float* __restrict__ c,                                      // [BATCH][NCELL]
    float* __restrict__ hf32,                                   // [BATCH][NCELL] (last step)
    int t, int last)
{
    __shared__ __align__(16) u16 As[2][2][128][40];  // [buf][plane][row][k] 40960 B
    __shared__ __align__(16) u16 Bs[2][2][64][40];   // [buf][plane][col][k] 20480 B

    const int tid = (int)threadIdx.x;
    const int nb = (int)blockIdx.x;       // cell block
    const int r0 = (int)blockIdx.y * 128; // row block
    const int lane = tid & 63, wv = tid >> 6;

    u16x8 aR[2][2];  // [plane][i]
    u16x8 bR[2];     // [plane]

    auto LOAD = [&](int ch) {
        const int k0 = ch * 32;
        #pragma unroll
        for (int p = 0; p < 2; ++p) {
            const u16* Hp = p ? Hlo : Hhi;
            #pragma unroll
            for (int i = 0; i < 2; ++i) {
                int cc = tid + 256 * i;                 // 0..511
                int row = cc >> 2, kk = (cc & 3) * 8;
                aR[p][i] = *(const u16x8*)&Hp[(size_t)(r0 + row) * KP + k0 + kk];
            }
        }
        #pragma unroll
        for (int p = 0; p < 2; ++p) {
            const u16* Wp = p ? Wtlo : Wthi;
            int col = tid >> 2, kk = (tid & 3) * 8;
            int zc = (col >> 4) * NCELL + nb * 16 + (col & 15);
            bR[p] = *(const u16x8*)&Wp[(size_t)zc * KP + k0 + kk];
        }
    };
    auto WRITE = [&](int b) {
        #pragma unroll
        for (int p = 0; p < 2; ++p)
            #pragma unroll
            for (int i = 0; i < 2; ++i) {
                int cc = tid + 256 * i;
                int row = cc >> 2, kk = (cc & 3) * 8;
                *(u16x8*)&As[b][p][row][kk] = aR[p][i];
            }
        #pragma unroll
        for (int p = 0; p < 2; ++p) {
            int col = tid >> 2, kk = (tid & 3) * 8;
            *(u16x8*)&Bs[b][p][col][kk] = bR[p];
        }
    };

    f32x4 acc[2][4] = {};   // [m-frag][gate]

    auto COMPUTE = [&](int b) {
        const int kof = (lane >> 4) * 8;
        s16x8 ah[2], al[2], bh[4], bl[4];
        #pragma unroll
        for (int m = 0; m < 2; ++m) {
            int row = wv * 32 + m * 16 + (lane & 15);
            ah[m] = *(const s16x8*)&As[b][0][row][kof];
            al[m] = *(const s16x8*)&As[b][1][row][kof];
        }
        #pragma unroll
        for (int n = 0; n < 4; ++n) {
            int col = n * 16 + (lane & 15);
            bh[n] = *(const s16x8*)&Bs[b][0][col][kof];
            bl[n] = *(const s16x8*)&Bs[b][1][col][kof];
        }
        #pragma unroll
        for (int m = 0; m < 2; ++m)
            #pragma unroll
            for (int n = 0; n < 4; ++n) {
                acc[m][n] = __builtin_amdgcn_mfma_f32_16x16x32_bf16(ah[m], bh[n], acc[m][n], 0, 0, 0);
                acc[m][n] = __builtin_amdgcn_mfma_f32_16x16x32_bf16(ah[m], bl[n], acc[m][n], 0, 0, 0);
                acc[m][n] = __builtin_amdgcn_mfma_f32_16x16x32_bf16(al[m], bh[n], acc[m][n], 0, 0, 0);
            }
    };

    LOAD(0); WRITE(0); __syncthreads();
    int b = 0;
    for (int ch = 0; ch < NCH; ++ch) {
        if (ch < NCH - 1) LOAD(ch + 1);
        COMPUTE(b);
        if (ch < NCH - 1) WRITE(b ^ 1);
        __syncthreads();
        b ^= 1;
    }

    // Fused gate epilogue. Gate g = acc[.][g]; TF order: i, j, f, o.
    const int cell = nb * 16 + (lane & 15);
    const float bi = bias[cell], bj = bias[NCELL + cell];
    const float bff = bias[2 * NCELL + cell], bo = bias[3 * NCELL + cell];
    #pragma unroll
    for (int m = 0; m < 2; ++m) {
        #pragma unroll
        for (int r = 0; r < 4; ++r) {
            int row = r0 + wv * 32 + m * 16 + (lane >> 4) * 4 + r;
            size_t ix = (size_t)row * NCELL + cell;
            float zi = acc[m][0][r] + bi;
            float zj = acc[m][1][r] + bj;
            float zf = acc[m][2][r] + bff;
            float zo = acc[m][3][r] + bo;
            float cn = c[ix] * sigm(zf + 1.0f) + sigm(zi) * ftanh(zj);
            c[ix] = cn;
            float h = ftanh(cn) * sigm(zo);
            u16 hh = f2b(h);
            u16 hl = f2b(h - b2f(hh));
            size_t hx = (size_t)row * KP + cell;
            Nhi[hx] = hh; Nlo[hx] = hl;
            if (last) hf32[ix] = h;
        }
    }
    // Write next step's x-slice into the next A planes.
    if (!last && nb < NFEAT && tid < 128) {
        int row = r0 + tid;
        float v = X[(size_t)row * (SEQ * NFEAT) + (t + 1) * NFEAT + nb];
        u16 vh = f2b(v), vl = f2b(v - b2f(vh));
        size_t hx = (size_t)row * KP + NCELL + nb;
        Nhi[hx] = vh; Nlo[hx] = vl;
    }
}

// ---------- fp32 tail GEMM: C = act(A @ Wm + bias), tile 64x64 ----------
template <int ACT>
__global__ __launch_bounds__(256) void gemm64(
    const float* __restrict__ A, const float* __restrict__ Wm,
    const float* __restrict__ bias, float* __restrict__ out,
    int M, int N, int K)
{
    __shared__ float Asf[32][65];
    __shared__ float Bsf[32][65];
    const int c0 = blockIdx.x * 64;
    const int r0 = blockIdx.y * 64;
    const int tid = (int)threadIdx.x;
    const int tx = tid & 15, ty = tid >> 4;

    float acc[4][4];
    #pragma unroll
    for (int r = 0; r < 4; ++r) { acc[r][0]=0.f; acc[r][1]=0.f; acc[r][2]=0.f; acc[r][3]=0.f; }

    for (int k0 = 0; k0 < K; k0 += 32) {
        #pragma unroll
        for (int i = 0; i < 8; ++i) {
            int e = tid + 256 * i;
            int row = e >> 5, kk = e & 31;
            Asf[kk][row] = A[(size_t)(r0 + row) * K + k0 + kk];
        }
        #pragma unroll
        for (int i = 0; i < 8; ++i) {
            int e = tid + 256 * i;
            int kk = e >> 6, cl = e & 63;
            Bsf[kk][cl] = Wm[(size_t)(k0 + kk) * N + c0 + cl];
        }
        __syncthreads();
        #pragma unroll
        for (int kk = 0; kk < 32; ++kk) {
            float b0 = Bsf[kk][tx*4], b1 = Bsf[kk][tx*4+1], b2 = Bsf[kk][tx*4+2], b3 = Bsf[kk][tx*4+3];
            #pragma unroll
            for (int r = 0; r < 4; ++r) {
                float a = Asf[kk][ty*4 + r];
                acc[r][0] = fmaf(a, b0, acc[r][0]);
                acc[r][1] = fmaf(a, b1, acc[r][1]);
                acc[r][2] = fmaf(a, b2, acc[r][2]);
                acc[r][3] = fmaf(a, b3, acc[r][3]);
            }
        }
        __syncthreads();
    }
    #pragma unroll
    for (int r = 0; r < 4; ++r) {
        int gr = r0 + ty * 4 + r;
        #pragma unroll
        for (int j = 0; j < 4; ++j) {
            int gc = c0 + tx * 4 + j;
            float v = acc[r][j] + bias[gc];
            if (ACT) v = fmaxf(v, 0.f);
            out[(size_t)gr * N + gc] = v;
        }
    }
}

extern "C" void kernel_launch(void* const* d_in, const int* in_sizes, int n_in,
                              void* d_out, int out_size, void* d_ws, size_t ws_size,
                              hipStream_t stream)
{
    const float* X  = (const float*)d_in[0];
    const float* Wl = (const float*)d_in[1];
    const float* bl = (const float*)d_in[2];
    const float* Wd = (const float*)d_in[3];
    const float* bd = (const float*)d_in[4];
    const float* Wp = (const float*)d_in[5];
    const float* bp = (const float*)d_in[6];
    float* out = (float*)d_out;

    // ws layout (21 MB total)
    char* p = (char*)d_ws;
    float* c     = (float*)p; p += (size_t)BATCH * NCELL * 4;        // 2 MB
    float* hf32  = (float*)p; p += (size_t)BATCH * NCELL * 4;        // 2 MB
    float* dense = (float*)p; p += (size_t)BATCH * DENSE_N * 4;      // 8 MB
    u16* Wthi = (u16*)p; p += (size_t)ZC * KP * 2;                   // 2.25 MB
    u16* Wtlo = (u16*)p; p += (size_t)ZC * KP * 2;
    u16* H0hi = (u16*)p; p += (size_t)BATCH * KP * 2;                // 1.125 MB
    u16* H0lo = (u16*)p; p += (size_t)BATCH * KP * 2;
    u16* H1hi = (u16*)p; p += (size_t)BATCH * KP * 2;
    u16* H1lo = (u16*)p; p += (size_t)BATCH * KP * 2;

    hipMemsetAsync(c, 0, (size_t)BATCH * NCELL * 4, stream);
    prep_w<<<(ZC * KP) / 256, 256, 0, stream>>>(Wl, Wthi, Wtlo);
    prep_h<<<(BATCH * KP) / 256, 256, 0, stream>>>(X, H0hi, H0lo, H1hi, H1lo);

    dim3 blk(256);
    dim3 gs(32, 8);
    for (int t = 0; t < SEQ; ++t) {
        const u16 *chi = (t & 1) ? H1hi : H0hi, *clo = (t & 1) ? H1lo : H0lo;
        u16 *nhi = (t & 1) ? H0hi : H1hi, *nlo = (t & 1) ? H0lo : H1lo;
        lstm_step_mfma<<<gs, blk, 0, stream>>>(chi, clo, nhi, nlo, Wthi, Wtlo,
                                               bl, X, c, hf32, t, t == SEQ - 1);
    }
    gemm64<1><<<dim3(DENSE_N / 64, BATCH / 64), blk, 0, stream>>>(hf32, Wd, bd, dense, BATCH, DENSE_N, NCELL);
    gemm64<0><<<dim3(PRED_N / 64, BATCH / 64), blk, 0, stream>>>(dense, Wp, bp, out, BATCH, PRED_N, DENSE_N);
}

// Round 3
// 10070.927 us; speedup vs baseline: 4.9399x; 1.1016x over previous
//
#include <hip/hip_runtime.h>

#define BATCH 1024
#define SEQ 512
#define NFEAT 24
#define NCELL 512
#define ZC 2048      // 4*NCELL
#define KP 576       // padded/reordered K: [h(512) | x(24) | pad(40)]
#define NCH 18       // K chunks of 32
#define DENSE_N 2048
#define PRED_N 576

typedef unsigned short u16;
typedef short s16x8 __attribute__((ext_vector_type(8)));
typedef float f32x4 __attribute__((ext_vector_type(4)));

__device__ __forceinline__ float sigm(float x) { return 1.f / (1.f + __expf(-x)); }
__device__ __forceinline__ float ftanh(float x) {
    float t = __expf(-2.f * fabsf(x));
    float r = (1.f - t) / (1.f + t);
    return copysignf(r, x);
}
__device__ __forceinline__ u16 f2b(float v) {           // f32 -> bf16 RTNE
    unsigned int x = __float_as_uint(v);
    unsigned int r = (x + 0x7fffu + ((x >> 16) & 1u)) >> 16;
    return (u16)r;
}
__device__ __forceinline__ float b2f(u16 u) { return __uint_as_float(((unsigned int)u) << 16); }

// ---------- prep: W -> transposed, K-reordered, split hi/lo ----------
__global__ __launch_bounds__(256) void prep_w(const float* __restrict__ W,
                                              u16* __restrict__ Whi, u16* __restrict__ Wlo) {
    int o = blockIdx.x * 256 + threadIdx.x;            // over ZC*KP
    if (o >= ZC * KP) return;
    int n = o / KP, k = o % KP;
    float v = 0.f;
    if (k < NCELL)            v = W[(size_t)(NFEAT + k) * ZC + n];     // h rows
    else if (k < NCELL + NFEAT) v = W[(size_t)(k - NCELL) * ZC + n];   // x rows
    u16 hi = f2b(v);
    u16 lo = f2b(v - b2f(hi));
    Whi[o] = hi; Wlo[o] = lo;
}

// ---------- prep: H0 = [h=0 | x_0 | 0], H1 = 0 ----------
__global__ __launch_bounds__(256) void prep_h(const float* __restrict__ X,
                                              u16* __restrict__ H0hi, u16* __restrict__ H0lo,
                                              u16* __restrict__ H1hi, u16* __restrict__ H1lo) {
    int o = blockIdx.x * 256 + threadIdx.x;            // over BATCH*KP
    if (o >= BATCH * KP) return;
    int row = o / KP, k = o % KP;
    u16 hi = 0, lo = 0;
    if (k >= NCELL && k < NCELL + NFEAT) {
        float v = X[(size_t)row * (SEQ * NFEAT) + (k - NCELL)];  // t = 0
        hi = f2b(v); lo = f2b(v - b2f(hi));
    }
    H0hi[o] = hi; H0lo[o] = lo;
    H1hi[o] = 0;  H1lo[o] = 0;
}

// ---------- LSTM step v3: A direct-from-global (wave-private rows),
// B double-buffered in LDS, reg-pipelined, fused gate epilogue. ----------
// Grid (32, 8): x = cell-block (16 cells x 4 gates = 64 z-cols), y = 128-row block.
__global__ __launch_bounds__(256) void lstm_step_v3(
    const u16* __restrict__ Hhi, const u16* __restrict__ Hlo,   // [BATCH][KP]
    u16* __restrict__ Nhi, u16* __restrict__ Nlo,               // next-step A planes
    const u16* __restrict__ Wthi, const u16* __restrict__ Wtlo, // [ZC][KP]
    const float* __restrict__ bias,                             // [ZC]
    const float* __restrict__ X,                                // [BATCH][SEQ][NFEAT]
    float* __restrict__ c,                                      // [BATCH][NCELL]
    float* __restrict__ hf32,                                   // [BATCH][NCELL] (last step)
    int t, int last)
{
    __shared__ __align__(16) u16 Bs[2][2][64][40];   // [buf][plane][col][k] 20.5 KB

    const int tid = (int)threadIdx.x;
    const int nb = (int)blockIdx.x;       // cell block
    const int r0 = (int)blockIdx.y * 128; // row block
    const int lane = tid & 63, wv = tid >> 6;

    // B staging addressing: one u16x8 per plane per thread per chunk
    const int bcol = tid >> 2, bkk = (tid & 3) * 8;
    const int zcb = (bcol >> 4) * NCELL + nb * 16 + (bcol & 15);
    const u16* bph = Wthi + (size_t)zcb * KP + bkk;
    const u16* bpl = Wtlo + (size_t)zcb * KP + bkk;

    // A-fragment addressing (wave-private rows): row = r0 + wv*32 + m*16 + (lane&15)
    const int akof = (lane >> 4) * 8;
    const size_t arow = (size_t)(r0 + wv * 32 + (lane & 15));
    const u16* a00 = Hhi + arow * KP + akof;          // m=0, hi
    const u16* a01 = Hlo + arow * KP + akof;          // m=0, lo
    const u16* a10 = a00 + (size_t)16 * KP;           // m=1, hi
    const u16* a11 = a01 + (size_t)16 * KP;           // m=1, lo

    f32x4 acc[2][4] = {};   // [m-frag][gate]
    s16x8 aA[2][2], aB[2][2], br0, br1;

#define ALOADTO(dst, ch) do { \
    dst[0][0] = *(const s16x8*)(a00 + (ch) * 32); \
    dst[0][1] = *(const s16x8*)(a01 + (ch) * 32); \
    dst[1][0] = *(const s16x8*)(a10 + (ch) * 32); \
    dst[1][1] = *(const s16x8*)(a11 + (ch) * 32); } while (0)
#define BLOADC(ch) do { \
    br0 = *(const s16x8*)(bph + (ch) * 32); \
    br1 = *(const s16x8*)(bpl + (ch) * 32); } while (0)
#define BWRITEC(b) do { \
    *(s16x8*)&Bs[b][0][bcol][bkk] = br0; \
    *(s16x8*)&Bs[b][1][bcol][bkk] = br1; } while (0)
#define COMPUTEC(b, ar) do { \
    s16x8 bh[4], bl[4]; \
    _Pragma("unroll") \
    for (int n = 0; n < 4; ++n) { \
        bh[n] = *(const s16x8*)&Bs[b][0][n * 16 + (lane & 15)][akof]; \
        bl[n] = *(const s16x8*)&Bs[b][1][n * 16 + (lane & 15)][akof]; \
    } \
    _Pragma("unroll") \
    for (int m = 0; m < 2; ++m) { \
        _Pragma("unroll") \
        for (int n = 0; n < 4; ++n) { \
            acc[m][n] = __builtin_amdgcn_mfma_f32_16x16x32_bf16(ar[m][0], bh[n], acc[m][n], 0, 0, 0); \
            acc[m][n] = __builtin_amdgcn_mfma_f32_16x16x32_bf16(ar[m][0], bl[n], acc[m][n], 0, 0, 0); \
            acc[m][n] = __builtin_amdgcn_mfma_f32_16x16x32_bf16(ar[m][1], bh[n], acc[m][n], 0, 0, 0); \
        } \
    } } while (0)

    // Prologue
    ALOADTO(aA, 0); BLOADC(0); BWRITEC(0);
    __syncthreads();

    #pragma unroll
    for (int ch = 0; ch < NCH; ch += 2) {
        if (ch + 1 < NCH) { ALOADTO(aB, ch + 1); BLOADC(ch + 1); }
        COMPUTEC(0, aA);
        if (ch + 1 < NCH) BWRITEC(1);
        __syncthreads();
        if (ch + 2 < NCH) { ALOADTO(aA, ch + 2); BLOADC(ch + 2); }
        if (ch + 1 < NCH) {
            COMPUTEC(1, aB);
            if (ch + 2 < NCH) BWRITEC(0);
            __syncthreads();
        }
    }

    // Fused gate epilogue. Gate g = acc[.][g]; TF order: i, j, f, o.
    const int cell = nb * 16 + (lane & 15);
    const float bi = bias[cell], bj = bias[NCELL + cell];
    const float bff = bias[2 * NCELL + cell], bo = bias[3 * NCELL + cell];
    #pragma unroll
    for (int m = 0; m < 2; ++m) {
        #pragma unroll
        for (int r = 0; r < 4; ++r) {
            int row = r0 + wv * 32 + m * 16 + (lane >> 4) * 4 + r;
            size_t ix = (size_t)row * NCELL + cell;
            float zi = acc[m][0][r] + bi;
            float zj = acc[m][1][r] + bj;
            float zf = acc[m][2][r] + bff;
            float zo = acc[m][3][r] + bo;
            float cn = c[ix] * sigm(zf + 1.0f) + sigm(zi) * ftanh(zj);
            c[ix] = cn;
            float h = ftanh(cn) * sigm(zo);
            u16 hh = f2b(h);
            u16 hl = f2b(h - b2f(hh));
            size_t hx = (size_t)row * KP + cell;
            Nhi[hx] = hh; Nlo[hx] = hl;
            if (last) hf32[ix] = h;
        }
    }
    // Write next step's x-slice into the next A planes.
    if (!last && nb < NFEAT && tid < 128) {
        int row = r0 + tid;
        float v = X[(size_t)row * (SEQ * NFEAT) + (t + 1) * NFEAT + nb];
        u16 vh = f2b(v), vl = f2b(v - b2f(vh));
        size_t hx = (size_t)row * KP + NCELL + nb;
        Nhi[hx] = vh; Nlo[hx] = vl;
    }
#undef ALOADTO
#undef BLOADC
#undef BWRITEC
#undef COMPUTEC
}

// ---------- fp32 tail GEMM: C = act(A @ Wm + bias), tile 64x64 ----------
template <int ACT>
__global__ __launch_bounds__(256) void gemm64(
    const float* __restrict__ A, const float* __restrict__ Wm,
    const float* __restrict__ bias, float* __restrict__ out,
    int M, int N, int K)
{
    __shared__ float Asf[32][65];
    __shared__ float Bsf[32][65];
    const int c0 = blockIdx.x * 64;
    const int r0 = blockIdx.y * 64;
    const int tid = (int)threadIdx.x;
    const int tx = tid & 15, ty = tid >> 4;

    float acc[4][4];
    #pragma unroll
    for (int r = 0; r < 4; ++r) { acc[r][0]=0.f; acc[r][1]=0.f; acc[r][2]=0.f; acc[r][3]=0.f; }

    for (int k0 = 0; k0 < K; k0 += 32) {
        #pragma unroll
        for (int i = 0; i < 8; ++i) {
            int e = tid + 256 * i;
            int row = e >> 5, kk = e & 31;
            Asf[kk][row] = A[(size_t)(r0 + row) * K + k0 + kk];
        }
        #pragma unroll
        for (int i = 0; i < 8; ++i) {
            int e = tid + 256 * i;
            int kk = e >> 6, cl = e & 63;
            Bsf[kk][cl] = Wm[(size_t)(k0 + kk) * N + c0 + cl];
        }
        __syncthreads();
        #pragma unroll
        for (int kk = 0; kk < 32; ++kk) {
            float b0 = Bsf[kk][tx*4], b1 = Bsf[kk][tx*4+1], b2 = Bsf[kk][tx*4+2], b3 = Bsf[kk][tx*4+3];
            #pragma unroll
            for (int r = 0; r < 4; ++r) {
                float a = Asf[kk][ty*4 + r];
                acc[r][0] = fmaf(a, b0, acc[r][0]);
                acc[r][1] = fmaf(a, b1, acc[r][1]);
                acc[r][2] = fmaf(a, b2, acc[r][2]);
                acc[r][3] = fmaf(a, b3, acc[r][3]);
            }
        }
        __syncthreads();
    }
    #pragma unroll
    for (int r = 0; r < 4; ++r) {
        int gr = r0 + ty * 4 + r;
        #pragma unroll
        for (int j = 0; j < 4; ++j) {
            int gc = c0 + tx * 4 + j;
            float v = acc[r][j] + bias[gc];
            if (ACT) v = fmaxf(v, 0.f);
            out[(size_t)gr * N + gc] = v;
        }
    }
}

extern "C" void kernel_launch(void* const* d_in, const int* in_sizes, int n_in,
                              void* d_out, int out_size, void* d_ws, size_t ws_size,
                              hipStream_t stream)
{
    const float* X  = (const float*)d_in[0];
    const float* Wl = (const float*)d_in[1];
    const float* bl = (const float*)d_in[2];
    const float* Wd = (const float*)d_in[3];
    const float* bd = (const float*)d_in[4];
    const float* Wp = (const float*)d_in[5];
    const float* bp = (const float*)d_in[6];
    float* out = (float*)d_out;

    // ws layout (21 MB total)
    char* p = (char*)d_ws;
    float* c     = (float*)p; p += (size_t)BATCH * NCELL * 4;        // 2 MB
    float* hf32  = (float*)p; p += (size_t)BATCH * NCELL * 4;        // 2 MB
    float* dense = (float*)p; p += (size_t)BATCH * DENSE_N * 4;      // 8 MB
    u16* Wthi = (u16*)p; p += (size_t)ZC * KP * 2;                   // 2.25 MB
    u16* Wtlo = (u16*)p; p += (size_t)ZC * KP * 2;
    u16* H0hi = (u16*)p; p += (size_t)BATCH * KP * 2;                // 1.125 MB
    u16* H0lo = (u16*)p; p += (size_t)BATCH * KP * 2;
    u16* H1hi = (u16*)p; p += (size_t)BATCH * KP * 2;
    u16* H1lo = (u16*)p; p += (size_t)BATCH * KP * 2;

    hipMemsetAsync(c, 0, (size_t)BATCH * NCELL * 4, stream);
    prep_w<<<(ZC * KP) / 256, 256, 0, stream>>>(Wl, Wthi, Wtlo);
    prep_h<<<(BATCH * KP) / 256, 256, 0, stream>>>(X, H0hi, H0lo, H1hi, H1lo);

    dim3 blk(256);
    dim3 gs(32, 8);
    for (int t = 0; t < SEQ; ++t) {
        const u16 *chi = (t & 1) ? H1hi : H0hi, *clo = (t & 1) ? H1lo : H0lo;
        u16 *nhi = (t & 1) ? H0hi : H1hi, *nlo = (t & 1) ? H0lo : H1lo;
        lstm_step_v3<<<gs, blk, 0, stream>>>(chi, clo, nhi, nlo, Wthi, Wtlo,
                                             bl, X, c, hf32, t, t == SEQ - 1);
    }
    gemm64<1><<<dim3(DENSE_N / 64, BATCH / 64), blk, 0, stream>>>(hf32, Wd, bd, dense, BATCH, DENSE_N, NCELL);
    gemm64<0><<<dim3(PRED_N / 64, BATCH / 64), blk, 0, stream>>>(dense, Wp, bp, out, BATCH, PRED_N, DENSE_N);
}